// Round 6
// baseline (273.089 us; speedup 1.0000x reference)
//
#include <hip/hip_runtime.h>

#define F 256
#define TWO_F 512
#define BM 128
#define BN 64
#define NBUCK 391        // src buckets: src>>7, src in [0,50000) -> 0..390
#define PAD 2560         // slots per bucket (mean fill 2046, sigma ~45 -> 11 sigma margin)
#define EPB 8192         // edges per sort block (256 thr x 32)

typedef __attribute__((ext_vector_type(8))) short short8;
typedef __attribute__((ext_vector_type(4))) float float4v;

// ---------- bf16 helpers ----------
static __device__ __forceinline__ unsigned short f2bf(float f) {
    unsigned u = __float_as_uint(f);
    u += 0x7FFFu + ((u >> 16) & 1u);
    return (unsigned short)(u >> 16);
}
// pack two floats -> two bf16 (round-half-up) in 2 adds + 1 v_perm
static __device__ __forceinline__ unsigned pack2(float lo, float hi) {
    unsigned a = __float_as_uint(lo) + 0x8000u;
    unsigned b = __float_as_uint(hi) + 0x8000u;
    return __builtin_amdgcn_perm(b, a, 0x07060302u);
}
static __device__ __forceinline__ float blo(unsigned u) { return __uint_as_float(u << 16); }
static __device__ __forceinline__ float rawf(unsigned u) { return __uint_as_float(u); }

// ---------- kernel 1: fused GEMM. C[m][n] = sum_k h[m][k]*W1v[n][k] (+b1 for n<256), bf16.
// No prep kernel, no hb/Wb buffers:
//  - A fragments: read h f32 directly (per-lane 2x float4), pack2 -> bf16 in-reg. Plain k
//    indexing (the k-rotation was only ever an LDS-bank device).
//  - W panel (64 rows x 256 k): converted f32->bf16 k-rotated into LDS by each block
//    (64KB f32 read, L2-resident across the 392 blocks sharing a panel; one-time cost).
// Barrier-free K-loop, 32KB LDS -> 4 blocks/CU. XCD pairing: all 8 by-blocks of one bx
// share (ib&7) -> same XCD -> h strip fetched from HBM once, L2-reused 8x.
__global__ __launch_bounds__(256, 4) void gemm_kernel(
    const float* __restrict__ h, const float* __restrict__ W1,
    const float* __restrict__ b1v, unsigned short* __restrict__ C, int M)
{
    __shared__ unsigned short sB[BN * F];   // 32 KB W panel; C-tile staging in epilogue

    const int ib = blockIdx.x;
    const int r8 = ib & 7;
    const int q  = ib >> 3;
    const int by = q & 7;
    const int bx = (q >> 3) * 8 + r8;
    const int bm = bx * BM;
    if (bm >= M) return;
    const int bn = by * BN;

    const int tid  = threadIdx.x;
    const int lane = tid & 63;
    const int wid  = tid >> 6;
    const int quad = lane >> 4;
    const int l15  = lane & 15;
    const int rot  = (l15 & 7) * 8;

    // in-block W panel conversion: thread covers row nn, one 64-k block kb
    {
        int nn = tid >> 2;                 // 0..63
        int kb = (tid & 3) * 64;           // 0,64,128,192
        int n  = bn + nn;
        const float* wrow = W1 + (size_t)(n & 255) * TWO_F + ((n >> 8) << 8) + kb;
        #pragma unroll
        for (int c = 0; c < 8; ++c) {
            float4 va = *(const float4*)(wrow + c * 8);
            float4 vb = *(const float4*)(wrow + c * 8 + 4);
            unsigned u0 = pack2(va.x, va.y), u1 = pack2(va.z, va.w);
            unsigned u2 = pack2(vb.x, vb.y), u3 = pack2(vb.z, vb.w);
            int p0 = (c * 8 + (nn & 7) * 8) & 63;   // rotation: multiple of 8 -> 16B chunk intact
            unsigned* dsp = (unsigned*)&sB[nn * F + kb + p0];
            dsp[0] = u0; dsp[1] = u1; dsp[2] = u2; dsp[3] = u3;
        }
    }

    // per-lane A row pointers into h (clamped; clamped rows' stores are guarded)
    const float* arow[2];
    #pragma unroll
    for (int mt = 0; mt < 2; ++mt) {
        int am = bm + wid * 32 + mt * 16 + l15;
        if (am > M - 1) am = M - 1;
        arow[mt] = h + (size_t)am * F;
    }

    float4v acc[2][4];
    #pragma unroll
    for (int i = 0; i < 2; ++i)
        #pragma unroll
        for (int j = 0; j < 4; ++j) acc[i][j] = (float4v)(0.f);

    __syncthreads();   // W panel ready

    #pragma unroll
    for (int kt = 0; kt < 4; ++kt) {
        #pragma unroll
        for (int ks = 0; ks < 2; ++ks) {
            const int ka  = kt * 64 + ks * 32 + quad * 8;                    // plain k for A
            const int kbo = kt * 64 + ((ks * 32 + quad * 8 + rot) & 63);     // rotated for B
            short8 afr[2], bfr[4];
            #pragma unroll
            for (int mt = 0; mt < 2; ++mt) {
                float4 fa = *(const float4*)(arow[mt] + ka);
                float4 fb = *(const float4*)(arow[mt] + ka + 4);
                unsigned* ap = (unsigned*)&afr[mt];
                ap[0] = pack2(fa.x, fa.y); ap[1] = pack2(fa.z, fa.w);
                ap[2] = pack2(fb.x, fb.y); ap[3] = pack2(fb.z, fb.w);
            }
            #pragma unroll
            for (int nt = 0; nt < 4; ++nt)
                bfr[nt] = *(const short8*)&sB[(nt * 16 + l15) * F + kbo];
            #pragma unroll
            for (int mt = 0; mt < 2; ++mt)
                #pragma unroll
                for (int nt = 0; nt < 4; ++nt)
                    acc[mt][nt] = __builtin_amdgcn_mfma_f32_16x16x32_bf16(
                        afr[mt], bfr[nt], acc[mt][nt], 0, 0, 0);
        }
    }

    // epilogue: +b1 for n<256 half, pack bf16 tile (128x64) into sB, coalesced stores
    float bias[4];
    #pragma unroll
    for (int nt = 0; nt < 4; ++nt) {
        int n = bn + nt * 16 + l15;
        bias[nt] = (n < F) ? b1v[n] : 0.f;
    }
    __syncthreads();   // all lanes done reading sB
    #pragma unroll
    for (int mt = 0; mt < 2; ++mt) {
        #pragma unroll
        for (int rr = 0; rr < 4; ++rr) {
            int row = wid * 32 + mt * 16 + quad * 4 + rr;
            #pragma unroll
            for (int nt = 0; nt < 4; ++nt)
                sB[row * BN + nt * 16 + l15] = f2bf(acc[mt][nt][rr] + bias[nt]);
        }
    }
    __syncthreads();
    #pragma unroll
    for (int p = 0; p < 4; ++p) {
        int row = p * 32 + (tid >> 3);
        int gm = bm + row;
        if (gm < M) {
            uint4 v = *(const uint4*)&sB[row * BN + (tid & 7) * 8];
            *(uint4*)(C + (size_t)gm * TWO_F + bn + (tid & 7) * 8) = v;
        }
    }
}

// ---------- kernel 2: single-pass padded-bucket sort by src bucket (src>>7) ----------
// Per-block LDS histogram -> ONE returning global atomic per (block,bucket) reserves a
// contiguous range at bucket*PAD (38k atomics total, ~98 per address). Ranks from LDS
// atomics. cursor[] ends as the per-bucket fill count, read by edge_kernel.
__global__ __launch_bounds__(256) void sort_scatter_kernel(
    const int* __restrict__ src, const int* __restrict__ dst,
    int* __restrict__ cursor, int2* __restrict__ sort_sd,
    int* __restrict__ sort_idx, int E)
{
    __shared__ int hist[512];
    __shared__ int base[512];
    const int tid = threadIdx.x;
    #pragma unroll
    for (int i = tid; i < 512; i += 256) hist[i] = 0;
    __syncthreads();
    const int bs = blockIdx.x * EPB;
    #pragma unroll
    for (int j = 0; j < EPB / 256; ++j) {
        int e = bs + j * 256 + tid;
        if (e < E) atomicAdd(&hist[((unsigned)src[e]) >> 7], 1);   // LDS atomic
    }
    __syncthreads();
    #pragma unroll
    for (int i = tid; i < 512; i += 256) {
        int c = hist[i];
        base[i] = c ? atomicAdd(&cursor[i], c) : 0;                // global, 1 per bucket
        hist[i] = 0;
    }
    __syncthreads();
    #pragma unroll
    for (int j = 0; j < EPB / 256; ++j) {
        int e = bs + j * 256 + tid;
        if (e < E) {
            int s = src[e];
            int bkt = ((unsigned)s) >> 7;
            int r = atomicAdd(&hist[bkt], 1);                      // LDS atomic
            int pos = bkt * PAD + base[bkt] + r;
            sort_sd[pos] = make_int2(s, dst[e]);
            sort_idx[pos] = e;
        }
    }
}

// ---------- kernel 3: per-edge score over padded sorted slots, 2 slots per 32-lane group ----
// Grid divisible by 8 -> XCD swizzle ACTIVE (was silently disabled at 50000 blocks):
// each XCD walks a contiguous span of sorted slots -> src rows L2-local per XCD.
__global__ __launch_bounds__(256) void edge_kernel(
    const unsigned short* __restrict__ C,
    const int2* __restrict__ sd, const int* __restrict__ sidx,
    const int* __restrict__ fill,
    const float* __restrict__ w2,
    const float* __restrict__ b2, float* __restrict__ out)
{
    const int lane = threadIdx.x & 31;
    const int nblk = gridDim.x;                          // 62560, %8==0
    const int ib = blockIdx.x;
    const int gb = (ib & 7) * (nblk >> 3) + (ib >> 3);
    const int g = gb * 8 + (threadIdx.x >> 5);
    const int sl0 = g * 2;                               // slot index (PAD even -> same bucket)
    const int bkt = sl0 / PAD;
    const int o = sl0 - bkt * PAD;
    const int cnt = fill[bkt];
    if (o >= cnt) return;
    const bool has1 = (o + 1 < cnt);
    int2 p0 = sd[sl0];
    int2 p1 = has1 ? sd[sl0 + 1] : p0;
    int i0 = sidx[sl0];
    int i1 = has1 ? sidx[sl0 + 1] : 0;

    uint4 av0 = *(const uint4*)(C + (size_t)p0.x * TWO_F + lane * 8);
    uint4 bv0 = *(const uint4*)(C + (size_t)p0.y * TWO_F + F + lane * 8);
    uint4 av1 = *(const uint4*)(C + (size_t)p1.x * TWO_F + lane * 8);
    uint4 bv1 = *(const uint4*)(C + (size_t)p1.y * TWO_F + F + lane * 8);
    float4 w0 = *(const float4*)(w2 + lane * 8);
    float4 w1 = *(const float4*)(w2 + lane * 8 + 4);

    float sum0, sum1;
    sum0  = w0.x * fmaxf(blo(av0.x) + blo(bv0.x), 0.f);
    sum0 += w0.y * fmaxf(rawf(av0.x) + rawf(bv0.x), 0.f);
    sum0 += w0.z * fmaxf(blo(av0.y) + blo(bv0.y), 0.f);
    sum0 += w0.w * fmaxf(rawf(av0.y) + rawf(bv0.y), 0.f);
    sum0 += w1.x * fmaxf(blo(av0.z) + blo(bv0.z), 0.f);
    sum0 += w1.y * fmaxf(rawf(av0.z) + rawf(bv0.z), 0.f);
    sum0 += w1.z * fmaxf(blo(av0.w) + blo(bv0.w), 0.f);
    sum0 += w1.w * fmaxf(rawf(av0.w) + rawf(bv0.w), 0.f);

    sum1  = w0.x * fmaxf(blo(av1.x) + blo(bv1.x), 0.f);
    sum1 += w0.y * fmaxf(rawf(av1.x) + rawf(bv1.x), 0.f);
    sum1 += w0.z * fmaxf(blo(av1.y) + blo(bv1.y), 0.f);
    sum1 += w0.w * fmaxf(rawf(av1.y) + rawf(bv1.y), 0.f);
    sum1 += w1.x * fmaxf(blo(av1.z) + blo(bv1.z), 0.f);
    sum1 += w1.y * fmaxf(rawf(av1.z) + rawf(bv1.z), 0.f);
    sum1 += w1.z * fmaxf(blo(av1.w) + blo(bv1.w), 0.f);
    sum1 += w1.w * fmaxf(rawf(av1.w) + rawf(bv1.w), 0.f);

    #pragma unroll
    for (int off = 16; off > 0; off >>= 1) {
        sum0 += __shfl_down(sum0, off, 32);
        sum1 += __shfl_down(sum1, off, 32);
    }

    if (lane == 0) {
        float b = b2[0];
        out[i0] = sum0 + b;
        if (has1) out[i1] = sum1 + b;
    }
}

extern "C" void kernel_launch(void* const* d_in, const int* in_sizes, int n_in,
                              void* d_out, int out_size, void* d_ws, size_t ws_size,
                              hipStream_t stream) {
    const float* h    = (const float*)d_in[0];
    const int*   src  = (const int*)d_in[1];
    const int*   dst  = (const int*)d_in[2];
    const float* W1_w = (const float*)d_in[3];
    const float* W1_b = (const float*)d_in[4];
    const float* W2_w = (const float*)d_in[5];
    const float* W2_b = (const float*)d_in[6];
    float* out = (float*)d_out;

    const int M = in_sizes[0] / F;   // 50000
    const int E = in_sizes[1];       // 800000

    // ws: [sd 391*2560*8B=8.0MB @+0][sidx 4.0MB @+9MB][cursor 2KB @+14MB][C 51.2MB @+26.5MB]
    int2* sort_sd  = (int2*)d_ws;
    int*  sort_idx = (int*)((char*)d_ws + 9 * 1024 * 1024);
    int*  cursor   = (int*)((char*)d_ws + 14 * 1024 * 1024);
    unsigned short* C = (unsigned short*)((char*)d_ws + 512 * 1024 + 26 * 1024 * 1024);

    hipMemsetAsync(cursor, 0, 512 * sizeof(int), stream);

    // fused gemm (h and W1 read directly; no prep kernel)
    int nbx = ((M + BM - 1) / BM + 7) / 8 * 8;     // 392
    gemm_kernel<<<nbx * 8, 256, 0, stream>>>(h, W1_w, W1_b, C, M);

    // single-kernel padded-bucket sort
    sort_scatter_kernel<<<(E + EPB - 1) / EPB, 256, 0, stream>>>(
        src, dst, cursor, sort_sd, sort_idx, E);

    // edge scoring over padded slots: 391*2560/16 = 62560 blocks (divisible by 8)
    edge_kernel<<<NBUCK * PAD / 16, 256, 0, stream>>>(
        C, sort_sd, sort_idx, cursor, W2_w, W2_b, out);
}

// Round 7
// 268.168 us; speedup vs baseline: 1.0183x; 1.0183x over previous
//
#include <hip/hip_runtime.h>

#define F 256
#define TWO_F 512
#define BM 128
#define BN 64
#define NBUCK 391        // src buckets: src>>7, src in [0,50000) -> 0..390
#define PAD 2560         // slots per bucket (mean fill 2046, sigma ~45 -> 11 sigma margin)
#define EPB 8192         // edges per sort block (1024 thr x 8)

typedef __attribute__((ext_vector_type(8))) short short8;
typedef __attribute__((ext_vector_type(4))) float float4v;

// ---------- bf16 helpers ----------
static __device__ __forceinline__ unsigned short f2bf(float f) {
    unsigned u = __float_as_uint(f);
    u += 0x7FFFu + ((u >> 16) & 1u);
    return (unsigned short)(u >> 16);
}
// pack two floats -> two bf16 (round-half-up) in 2 adds + 1 v_perm
static __device__ __forceinline__ unsigned pack2(float lo, float hi) {
    unsigned a = __float_as_uint(lo) + 0x8000u;
    unsigned b = __float_as_uint(hi) + 0x8000u;
    return __builtin_amdgcn_perm(b, a, 0x07060302u);
}
static __device__ __forceinline__ float blo(unsigned u) { return __uint_as_float(u << 16); }
static __device__ __forceinline__ float rawf(unsigned u) { return __uint_as_float(u); }

// ---------- kernel 1: fused GEMM. C[m][n] = sum_k h[m][k]*W1[n][k] (+b1 for n<256), bf16.
// R6 counters: 88us, MfmaUtil 5.7%, VALUBusy 12%, HBM 11% -> latency-bound on the serialized
// per-iteration A-load -> pack -> MFMA chain (compiler kept 44 VGPRs, no pipelining).
// Fix: register double-buffer the A tile; issue kt+1's loads BEFORE computing kt.
__global__ __launch_bounds__(256, 4) void gemm_kernel(
    const float* __restrict__ h, const float* __restrict__ W1,
    const float* __restrict__ b1v, unsigned short* __restrict__ C, int M)
{
    __shared__ unsigned short sB[BN * F];   // 32 KB W panel; C-tile staging in epilogue

    const int ib = blockIdx.x;
    const int r8 = ib & 7;
    const int q  = ib >> 3;
    const int by = q & 7;
    const int bx = (q >> 3) * 8 + r8;
    const int bm = bx * BM;
    if (bm >= M) return;
    const int bn = by * BN;

    const int tid  = threadIdx.x;
    const int lane = tid & 63;
    const int wid  = tid >> 6;
    const int quad = lane >> 4;
    const int l15  = lane & 15;
    const int rot  = (l15 & 7) * 8;

    // in-block W panel conversion: thread covers row nn, one 64-k block kb
    {
        int nn = tid >> 2;                 // 0..63
        int kb = (tid & 3) * 64;           // 0,64,128,192
        int n  = bn + nn;
        const float* wrow = W1 + (size_t)(n & 255) * TWO_F + ((n >> 8) << 8) + kb;
        #pragma unroll
        for (int c = 0; c < 8; ++c) {
            float4 va = *(const float4*)(wrow + c * 8);
            float4 vb = *(const float4*)(wrow + c * 8 + 4);
            unsigned u0 = pack2(va.x, va.y), u1 = pack2(va.z, va.w);
            unsigned u2 = pack2(vb.x, vb.y), u3 = pack2(vb.z, vb.w);
            int p0 = (c * 8 + (nn & 7) * 8) & 63;   // rotation: multiple of 8 -> 16B chunk intact
            unsigned* dsp = (unsigned*)&sB[nn * F + kb + p0];
            dsp[0] = u0; dsp[1] = u1; dsp[2] = u2; dsp[3] = u3;
        }
    }

    // per-lane A row pointers into h (clamped; clamped rows' stores are guarded)
    const float* arow[2];
    #pragma unroll
    for (int mt = 0; mt < 2; ++mt) {
        int am = bm + wid * 32 + mt * 16 + l15;
        if (am > M - 1) am = M - 1;
        arow[mt] = h + (size_t)am * F;
    }

    float4v acc[2][4];
    #pragma unroll
    for (int i = 0; i < 2; ++i)
        #pragma unroll
        for (int j = 0; j < 4; ++j) acc[i][j] = (float4v)(0.f);

    // register double-buffer for the A tile: [parity][ks][mt][half], 16 float4 = 64 VGPR
    float4 a[2][2][2][2];

    // prologue: issue kt=0 loads BEFORE the barrier (overlap the W-conversion drain)
    #pragma unroll
    for (int ks = 0; ks < 2; ++ks)
        #pragma unroll
        for (int mt = 0; mt < 2; ++mt) {
            const int ka = ks * 32 + quad * 8;
            a[0][ks][mt][0] = *(const float4*)(arow[mt] + ka);
            a[0][ks][mt][1] = *(const float4*)(arow[mt] + ka + 4);
        }

    __syncthreads();   // W panel ready

    #pragma unroll
    for (int kt = 0; kt < 4; ++kt) {
        const int par = kt & 1;                  // compile-time after unroll
        if (kt < 3) {                            // issue next tile's loads first
            #pragma unroll
            for (int ks = 0; ks < 2; ++ks)
                #pragma unroll
                for (int mt = 0; mt < 2; ++mt) {
                    const int ka = (kt + 1) * 64 + ks * 32 + quad * 8;
                    a[par ^ 1][ks][mt][0] = *(const float4*)(arow[mt] + ka);
                    a[par ^ 1][ks][mt][1] = *(const float4*)(arow[mt] + ka + 4);
                }
        }
        #pragma unroll
        for (int ks = 0; ks < 2; ++ks) {
            const int kbo = kt * 64 + ((ks * 32 + quad * 8 + rot) & 63);   // rotated for B
            short8 afr[2], bfr[4];
            #pragma unroll
            for (int mt = 0; mt < 2; ++mt) {
                float4 fa = a[par][ks][mt][0];
                float4 fb = a[par][ks][mt][1];
                unsigned* ap = (unsigned*)&afr[mt];
                ap[0] = pack2(fa.x, fa.y); ap[1] = pack2(fa.z, fa.w);
                ap[2] = pack2(fb.x, fb.y); ap[3] = pack2(fb.z, fb.w);
            }
            #pragma unroll
            for (int nt = 0; nt < 4; ++nt)
                bfr[nt] = *(const short8*)&sB[(nt * 16 + l15) * F + kbo];
            #pragma unroll
            for (int mt = 0; mt < 2; ++mt)
                #pragma unroll
                for (int nt = 0; nt < 4; ++nt)
                    acc[mt][nt] = __builtin_amdgcn_mfma_f32_16x16x32_bf16(
                        afr[mt], bfr[nt], acc[mt][nt], 0, 0, 0);
        }
    }

    // epilogue: +b1 for n<256 half, pack bf16 tile (128x64) into sB, coalesced stores
    float bias[4];
    #pragma unroll
    for (int nt = 0; nt < 4; ++nt) {
        int n = bn + nt * 16 + l15;
        bias[nt] = (n < F) ? b1v[n] : 0.f;
    }
    __syncthreads();   // all lanes done reading sB
    #pragma unroll
    for (int mt = 0; mt < 2; ++mt) {
        #pragma unroll
        for (int rr = 0; rr < 4; ++rr) {
            int row = wid * 32 + mt * 16 + quad * 4 + rr;
            #pragma unroll
            for (int nt = 0; nt < 4; ++nt)
                sB[row * BN + nt * 16 + l15] = f2bf(acc[mt][nt][rr] + bias[nt]);
        }
    }
    __syncthreads();
    #pragma unroll
    for (int p = 0; p < 4; ++p) {
        int row = p * 32 + (tid >> 3);
        int gm = bm + row;
        if (gm < M) {
            uint4 v = *(const uint4*)&sB[row * BN + (tid & 7) * 8];
            *(uint4*)(C + (size_t)gm * TWO_F + bn + (tid & 7) * 8) = v;
        }
    }
}

// ---------- kernel 2: single-pass padded-bucket sort by src bucket (src>>7) ----------
// 1024 threads/block (was 256: at 98 blocks that left 62% of the GPU idle and 32 serial
// iters/thread). Per-block LDS histogram -> ONE returning global atomic per (block,bucket)
// (chain depth 98 per bucket ~= 14us worst case). Ranks from LDS atomics. cursor[] ends as
// the per-bucket fill count, read by edge_kernel.
__global__ __launch_bounds__(1024) void sort_scatter_kernel(
    const int* __restrict__ src, const int* __restrict__ dst,
    int* __restrict__ cursor, int2* __restrict__ sort_sd,
    int* __restrict__ sort_idx, int E)
{
    __shared__ int hist[512];
    __shared__ int base[512];
    const int tid = threadIdx.x;
    if (tid < 512) hist[tid] = 0;
    __syncthreads();
    const int bs = blockIdx.x * EPB;
    #pragma unroll
    for (int j = 0; j < EPB / 1024; ++j) {
        int e = bs + j * 1024 + tid;
        if (e < E) atomicAdd(&hist[((unsigned)src[e]) >> 7], 1);   // LDS atomic
    }
    __syncthreads();
    if (tid < 512) {
        int c = hist[tid];
        base[tid] = c ? atomicAdd(&cursor[tid], c) : 0;            // global, 1 per bucket
        hist[tid] = 0;
    }
    __syncthreads();
    #pragma unroll
    for (int j = 0; j < EPB / 1024; ++j) {
        int e = bs + j * 1024 + tid;
        if (e < E) {
            int s = src[e];
            int bkt = ((unsigned)s) >> 7;
            int r = atomicAdd(&hist[bkt], 1);                      // LDS atomic
            int pos = bkt * PAD + base[bkt] + r;
            sort_sd[pos] = make_int2(s, dst[e]);
            sort_idx[pos] = e;
        }
    }
}

// ---------- kernel 3: per-edge score over padded sorted slots, 2 slots per 32-lane group ----
// Grid divisible by 8 -> XCD swizzle active: each XCD walks a contiguous span of sorted
// slots -> src rows L2-local per XCD.
__global__ __launch_bounds__(256) void edge_kernel(
    const unsigned short* __restrict__ C,
    const int2* __restrict__ sd, const int* __restrict__ sidx,
    const int* __restrict__ fill,
    const float* __restrict__ w2,
    const float* __restrict__ b2, float* __restrict__ out)
{
    const int lane = threadIdx.x & 31;
    const int nblk = gridDim.x;                          // 62560, %8==0
    const int ib = blockIdx.x;
    const int gb = (ib & 7) * (nblk >> 3) + (ib >> 3);
    const int g = gb * 8 + (threadIdx.x >> 5);
    const int sl0 = g * 2;                               // slot index (PAD even -> same bucket)
    const int bkt = sl0 / PAD;
    const int o = sl0 - bkt * PAD;
    const int cnt = fill[bkt];
    if (o >= cnt) return;
    const bool has1 = (o + 1 < cnt);
    int2 p0 = sd[sl0];
    int2 p1 = has1 ? sd[sl0 + 1] : p0;
    int i0 = sidx[sl0];
    int i1 = has1 ? sidx[sl0 + 1] : 0;

    uint4 av0 = *(const uint4*)(C + (size_t)p0.x * TWO_F + lane * 8);
    uint4 bv0 = *(const uint4*)(C + (size_t)p0.y * TWO_F + F + lane * 8);
    uint4 av1 = *(const uint4*)(C + (size_t)p1.x * TWO_F + lane * 8);
    uint4 bv1 = *(const uint4*)(C + (size_t)p1.y * TWO_F + F + lane * 8);
    float4 w0 = *(const float4*)(w2 + lane * 8);
    float4 w1 = *(const float4*)(w2 + lane * 8 + 4);

    float sum0, sum1;
    sum0  = w0.x * fmaxf(blo(av0.x) + blo(bv0.x), 0.f);
    sum0 += w0.y * fmaxf(rawf(av0.x) + rawf(bv0.x), 0.f);
    sum0 += w0.z * fmaxf(blo(av0.y) + blo(bv0.y), 0.f);
    sum0 += w0.w * fmaxf(rawf(av0.y) + rawf(bv0.y), 0.f);
    sum0 += w1.x * fmaxf(blo(av0.z) + blo(bv0.z), 0.f);
    sum0 += w1.y * fmaxf(rawf(av0.z) + rawf(bv0.z), 0.f);
    sum0 += w1.z * fmaxf(blo(av0.w) + blo(bv0.w), 0.f);
    sum0 += w1.w * fmaxf(rawf(av0.w) + rawf(bv0.w), 0.f);

    sum1  = w0.x * fmaxf(blo(av1.x) + blo(bv1.x), 0.f);
    sum1 += w0.y * fmaxf(rawf(av1.x) + rawf(bv1.x), 0.f);
    sum1 += w0.z * fmaxf(blo(av1.y) + blo(bv1.y), 0.f);
    sum1 += w0.w * fmaxf(rawf(av1.y) + rawf(bv1.y), 0.f);
    sum1 += w1.x * fmaxf(blo(av1.z) + blo(bv1.z), 0.f);
    sum1 += w1.y * fmaxf(rawf(av1.z) + rawf(bv1.z), 0.f);
    sum1 += w1.z * fmaxf(blo(av1.w) + blo(bv1.w), 0.f);
    sum1 += w1.w * fmaxf(rawf(av1.w) + rawf(bv1.w), 0.f);

    #pragma unroll
    for (int off = 16; off > 0; off >>= 1) {
        sum0 += __shfl_down(sum0, off, 32);
        sum1 += __shfl_down(sum1, off, 32);
    }

    if (lane == 0) {
        float b = b2[0];
        out[i0] = sum0 + b;
        if (has1) out[i1] = sum1 + b;
    }
}

extern "C" void kernel_launch(void* const* d_in, const int* in_sizes, int n_in,
                              void* d_out, int out_size, void* d_ws, size_t ws_size,
                              hipStream_t stream) {
    const float* h    = (const float*)d_in[0];
    const int*   src  = (const int*)d_in[1];
    const int*   dst  = (const int*)d_in[2];
    const float* W1_w = (const float*)d_in[3];
    const float* W1_b = (const float*)d_in[4];
    const float* W2_w = (const float*)d_in[5];
    const float* W2_b = (const float*)d_in[6];
    float* out = (float*)d_out;

    const int M = in_sizes[0] / F;   // 50000
    const int E = in_sizes[1];       // 800000

    // ws: [sd 391*2560*8B=8.0MB @+0][sidx 4.0MB @+9MB][cursor 2KB @+14MB][C 51.2MB @+26.5MB]
    int2* sort_sd  = (int2*)d_ws;
    int*  sort_idx = (int*)((char*)d_ws + 9 * 1024 * 1024);
    int*  cursor   = (int*)((char*)d_ws + 14 * 1024 * 1024);
    unsigned short* C = (unsigned short*)((char*)d_ws + 512 * 1024 + 26 * 1024 * 1024);

    hipMemsetAsync(cursor, 0, 512 * sizeof(int), stream);

    // fused gemm (h and W1 read directly; no prep kernel)
    int nbx = ((M + BM - 1) / BM + 7) / 8 * 8;     // 392
    gemm_kernel<<<nbx * 8, 256, 0, stream>>>(h, W1_w, W1_b, C, M);

    // single-kernel padded-bucket sort (1024 threads/block)
    sort_scatter_kernel<<<(E + EPB - 1) / EPB, 1024, 0, stream>>>(
        src, dst, cursor, sort_sd, sort_idx, E);

    // edge scoring over padded slots: 391*2560/16 = 62560 blocks (divisible by 8)
    edge_kernel<<<NBUCK * PAD / 16, 256, 0, stream>>>(
        C, sort_sd, sort_idx, cursor, W2_w, W2_b, out);
}

// Round 9
// 227.024 us; speedup vs baseline: 1.2029x; 1.1812x over previous
//
#include <hip/hip_runtime.h>

#define F 256
#define TWO_F 512
#define BM 128
#define BN 64
#define BK 64

typedef __attribute__((ext_vector_type(8))) short short8;
typedef __attribute__((ext_vector_type(4))) float float4v;

// ---------- bf16 helpers ----------
static __device__ __forceinline__ unsigned short f2bf(float f) {
    unsigned u = __float_as_uint(f);
    u += 0x7FFFu + ((u >> 16) & 1u);
    return (unsigned short)(u >> 16);
}
// pack two floats -> two bf16 (round-half-up) in 2 adds + 1 v_perm
static __device__ __forceinline__ unsigned pack2(float lo, float hi) {
    unsigned a = __float_as_uint(lo) + 0x8000u;
    unsigned b = __float_as_uint(hi) + 0x8000u;
    return __builtin_amdgcn_perm(b, a, 0x07060302u);
}
static __device__ __forceinline__ float blo(unsigned u) { return __uint_as_float(u << 16); }
static __device__ __forceinline__ float rawf(unsigned u) { return __uint_as_float(u); }

// ---------- kernel 1 (merged prep): h fp32->hb bf16 and W1 fp32->Wb bf16, both k-rotated ----
// rotation: within each 64-elem k-block, elem k -> (k + (row&7)*8) & 63  (row = m for hb, n
// for Wb). bf16 inputs are required so gemm's global_load_lds stages 8 contiguous rows x
// 128B per instruction (per-register A loads are 64-line divergent -> R5-R7's wall).
__global__ __launch_bounds__(256) void prep_kernel(
    const float* __restrict__ h, const float* __restrict__ W1,
    unsigned short* __restrict__ hb, unsigned short* __restrict__ Wb, int M)
{
    int i = blockIdx.x * blockDim.x + threadIdx.x;
    if (i < M * 128) {                       // h part: one bf16 pair per thread
        int m = i >> 7;
        int kp = (i & 127) * 2;
        float2 v = *(const float2*)(h + (size_t)m * F + kp);
        unsigned pk = pack2(v.x, v.y);
        int ksw = ((kp & 63) + (m & 7) * 8) & 63;   // rotation multiple of 8 -> pair intact
        *(unsigned*)(hb + (size_t)m * F + (kp & ~63) + ksw) = pk;
    }
    if (i < TWO_F * F) {                     // W part
        int n = i >> 8;
        int k = i & 255;
        float v = W1[(n & 255) * TWO_F + ((n >> 8) << 8) + k];
        int kin_sw = ((k & 63) + (n & 7) * 8) & 63;
        Wb[n * F + (k & ~63) + kin_sw] = f2bf(v);
    }
}

// ---------- kernel 2: C[m][n] = sum_k hb[m][k]*Wb[n][k] (+b1 for n<256), bf16 out ----------
// T3+T4 (§5.5): double-buffered LDS + counted vmcnt + raw s_barrier, with R8's bug fixed:
//  (a) VMEM issue order PINNED via sched_barrier(0) after bias and after each stage group
//      (vmcnt(N) semantics require the awaited tile's loads to be the oldest outstanding;
//      without pinning the scheduler interleaves the 12 global_load_lds -> R8's corruption).
//  (b) lgkmcnt(0) drained before every overwrite-permitting barrier (m201 discipline).
// Next tile's loads stay in flight ACROSS the compute barrier; no vmcnt(0) until the last
// tile. LDS 48KB -> 3 blocks/CU.
__global__ __launch_bounds__(256, 3) void gemm_kernel(
    const unsigned short* __restrict__ hb, const unsigned short* __restrict__ Wb,
    const float* __restrict__ b1v, unsigned short* __restrict__ C, int M)
{
    __shared__ unsigned short sA[2][BM * BK];   // 2 x 16 KB (sA[0] reused as C tile)
    __shared__ unsigned short sB[2][BN * BK];   // 2 x  8 KB

    // XCD pairing: all 8 by-blocks of one bx share (ib&7) -> same XCD -> hb strip L2-reused 8x.
    const int ib = blockIdx.x;
    const int r8 = ib & 7;
    const int q  = ib >> 3;
    const int by = q & 7;
    const int bx = (q >> 3) * 8 + r8;
    const int bm = bx * BM;
    if (bm >= M) return;
    const int bn = by * BN;

    const int tid  = threadIdx.x;
    const int lane = tid & 63;
    const int wid  = tid >> 6;
    const int st_r = lane >> 3;
    const int st_k = (lane & 7) * 8;
    const int quad = lane >> 4;
    const int l15  = lane & 15;
    const int rot  = (l15 & 7) * 8;

    float4v acc[2][4];
    #pragma unroll
    for (int i = 0; i < 2; ++i)
        #pragma unroll
        for (int j = 0; j < 4; ++j) acc[i][j] = (float4v)(0.f);

    // per-wave: 4 sA issues + 2 sB issues = 6 VMEM ops per stage group
    auto stage = [&](int buf, int k0) {
        #pragma unroll
        for (int p = 0; p < 4; ++p) {
            int r = wid * 32 + p * 8;
            int am = bm + r + st_r; if (am > M - 1) am = M - 1;   // clamp; stores guarded
            const unsigned short* ga = hb + (size_t)am * F + k0 + st_k;
            __builtin_amdgcn_global_load_lds(
                (const __attribute__((address_space(1))) unsigned int*)ga,
                (__attribute__((address_space(3))) unsigned int*)&sA[buf][r * BK],
                16, 0, 0);
        }
        #pragma unroll
        for (int p = 0; p < 2; ++p) {
            int r = wid * 16 + p * 8;
            const unsigned short* gb = Wb + (size_t)(bn + r + st_r) * F + k0 + st_k;
            __builtin_amdgcn_global_load_lds(
                (const __attribute__((address_space(1))) unsigned int*)gb,
                (__attribute__((address_space(3))) unsigned int*)&sB[buf][r * BK],
                16, 0, 0);
        }
    };

    auto compute = [&](int cur) {
        #pragma unroll
        for (int ks = 0; ks < 2; ++ks) {
            const int koff = (ks * 32 + quad * 8 + rot) & 63;
            short8 afr[2], bfr[4];
            #pragma unroll
            for (int mt = 0; mt < 2; ++mt)
                afr[mt] = *(const short8*)&sA[cur][(wid * 32 + mt * 16 + l15) * BK + koff];
            #pragma unroll
            for (int nt = 0; nt < 4; ++nt)
                bfr[nt] = *(const short8*)&sB[cur][(nt * 16 + l15) * BK + koff];
            #pragma unroll
            for (int mt = 0; mt < 2; ++mt)
                #pragma unroll
                for (int nt = 0; nt < 4; ++nt)
                    acc[mt][nt] = __builtin_amdgcn_mfma_f32_16x16x32_bf16(
                        afr[mt], bfr[nt], acc[mt][nt], 0, 0, 0);
        }
    };

    // bias loads pinned FIRST in the per-wave VMEM stream (retire before/with tile0)
    float bias[4];
    #pragma unroll
    for (int nt = 0; nt < 4; ++nt) {
        int n = bn + nt * 16 + l15;
        bias[nt] = (n < F) ? b1v[n] : 0.f;
    }
    __builtin_amdgcn_sched_barrier(0);

    // prologue: two tiles in flight, pinned order [bias][tile0 x6][tile1 x6]
    stage(0, 0);
    __builtin_amdgcn_sched_barrier(0);
    stage(1, 64);
    __builtin_amdgcn_sched_barrier(0);
    asm volatile("s_waitcnt vmcnt(6)" ::: "memory");       // bias+tile0 retired
    __builtin_amdgcn_s_barrier();                          // B1: tile0 visible to all

    compute(0);                                            // kt=0 (tile1 in flight)
    asm volatile("s_waitcnt lgkmcnt(0)" ::: "memory");     // own buf0 ds_reads done
    __builtin_amdgcn_sched_barrier(0);
    __builtin_amdgcn_s_barrier();                          // B2: all waves done with buf0
    stage(0, 128);                                         // tile2 -> buf0
    __builtin_amdgcn_sched_barrier(0);
    asm volatile("s_waitcnt vmcnt(6)" ::: "memory");       // tile1 retired (tile2 in flight)
    __builtin_amdgcn_s_barrier();                          // B3: tile1 visible

    compute(1);                                            // kt=1 (tile2 in flight)
    asm volatile("s_waitcnt lgkmcnt(0)" ::: "memory");
    __builtin_amdgcn_sched_barrier(0);
    __builtin_amdgcn_s_barrier();                          // B4: all waves done with buf1
    stage(1, 192);                                         // tile3 -> buf1
    __builtin_amdgcn_sched_barrier(0);
    asm volatile("s_waitcnt vmcnt(6)" ::: "memory");       // tile2 retired (tile3 in flight)
    __builtin_amdgcn_s_barrier();                          // B5: tile2 visible

    compute(0);                                            // kt=2 (tile3 in flight)
    asm volatile("s_waitcnt vmcnt(0)" ::: "memory");       // tile3 retired
    __builtin_amdgcn_s_barrier();                          // B6: tile3 visible

    compute(1);                                            // kt=3

    // epilogue: +b1 for n<256 half, pack bf16 tile (128x64) into sA[0], coalesced stores.
    // __syncthreads drains every wave's lgkmcnt before the barrier -> safe to overwrite sA[0].
    __syncthreads();
    #pragma unroll
    for (int mt = 0; mt < 2; ++mt) {
        #pragma unroll
        for (int rr = 0; rr < 4; ++rr) {
            int row = wid * 32 + mt * 16 + quad * 4 + rr;
            #pragma unroll
            for (int nt = 0; nt < 4; ++nt)
                sA[0][row * BK + nt * 16 + l15] = f2bf(acc[mt][nt][rr] + bias[nt]);
        }
    }
    __syncthreads();
    #pragma unroll
    for (int p = 0; p < 4; ++p) {
        int row = p * 32 + (tid >> 3);
        int gm = bm + row;
        if (gm < M) {
            uint4 v = *(const uint4*)&sA[0][row * BK + (tid & 7) * 8];
            *(uint4*)(C + (size_t)gm * TWO_F + bn + (tid & 7) * 8) = v;
        }
    }
}

// ---------- kernel 3: per-edge score, 2 edges per 32-lane group (R0 proven version) ------
__global__ __launch_bounds__(256) void edge_kernel(
    const unsigned short* __restrict__ C,
    const int* __restrict__ src, const int* __restrict__ dst,
    const float* __restrict__ w2,
    const float* __restrict__ b2, float* __restrict__ out, int E)
{
    const int lane = threadIdx.x & 31;
    const int g = blockIdx.x * 8 + (threadIdx.x >> 5);
    const int e0 = g * 2;
    if (e0 >= E) return;
    const int s0 = src[e0], d0 = dst[e0];
    const int s1 = src[e0 + 1], d1 = dst[e0 + 1];

    uint4 av0 = *(const uint4*)(C + (size_t)s0 * TWO_F + lane * 8);
    uint4 bv0 = *(const uint4*)(C + (size_t)d0 * TWO_F + F + lane * 8);
    uint4 av1 = *(const uint4*)(C + (size_t)s1 * TWO_F + lane * 8);
    uint4 bv1 = *(const uint4*)(C + (size_t)d1 * TWO_F + F + lane * 8);
    float4 w0 = *(const float4*)(w2 + lane * 8);
    float4 w1 = *(const float4*)(w2 + lane * 8 + 4);

    float sum0, sum1;
    sum0  = w0.x * fmaxf(blo(av0.x) + blo(bv0.x), 0.f);
    sum0 += w0.y * fmaxf(rawf(av0.x) + rawf(bv0.x), 0.f);
    sum0 += w0.z * fmaxf(blo(av0.y) + blo(bv0.y), 0.f);
    sum0 += w0.w * fmaxf(rawf(av0.y) + rawf(bv0.y), 0.f);
    sum0 += w1.x * fmaxf(blo(av0.z) + blo(bv0.z), 0.f);
    sum0 += w1.y * fmaxf(rawf(av0.z) + rawf(bv0.z), 0.f);
    sum0 += w1.z * fmaxf(blo(av0.w) + blo(bv0.w), 0.f);
    sum0 += w1.w * fmaxf(rawf(av0.w) + rawf(bv0.w), 0.f);

    sum1  = w0.x * fmaxf(blo(av1.x) + blo(bv1.x), 0.f);
    sum1 += w0.y * fmaxf(rawf(av1.x) + rawf(bv1.x), 0.f);
    sum1 += w0.z * fmaxf(blo(av1.y) + blo(bv1.y), 0.f);
    sum1 += w0.w * fmaxf(rawf(av1.y) + rawf(bv1.y), 0.f);
    sum1 += w1.x * fmaxf(blo(av1.z) + blo(bv1.z), 0.f);
    sum1 += w1.y * fmaxf(rawf(av1.z) + rawf(bv1.z), 0.f);
    sum1 += w1.z * fmaxf(blo(av1.w) + blo(bv1.w), 0.f);
    sum1 += w1.w * fmaxf(rawf(av1.w) + rawf(bv1.w), 0.f);

    #pragma unroll
    for (int off = 16; off > 0; off >>= 1) {
        sum0 += __shfl_down(sum0, off, 32);
        sum1 += __shfl_down(sum1, off, 32);
    }

    if (lane == 0) {
        float b = b2[0];
        out[e0]     = sum0 + b;
        out[e0 + 1] = sum1 + b;
    }
}

extern "C" void kernel_launch(void* const* d_in, const int* in_sizes, int n_in,
                              void* d_out, int out_size, void* d_ws, size_t ws_size,
                              hipStream_t stream) {
    const float* h    = (const float*)d_in[0];
    const int*   src  = (const int*)d_in[1];
    const int*   dst  = (const int*)d_in[2];
    const float* W1_w = (const float*)d_in[3];
    const float* W1_b = (const float*)d_in[4];
    const float* W2_w = (const float*)d_in[5];
    const float* W2_b = (const float*)d_in[6];
    float* out = (float*)d_out;

    const int M = in_sizes[0] / F;   // 50000
    const int E = in_sizes[1];       // 800000

    // ws: [Wb bf16 256KB][pad to 512KB][hb bf16 25.6MB, pad to 26MB][C bf16 51.2MB]
    unsigned short* Wb = (unsigned short*)d_ws;
    unsigned short* hb = (unsigned short*)((char*)d_ws + 512 * 1024);
    unsigned short* C  = (unsigned short*)((char*)d_ws + 512 * 1024 + 26 * 1024 * 1024);

    // merged prep
    int prep_threads = M * 128 > TWO_F * F ? M * 128 : TWO_F * F;
    prep_kernel<<<(prep_threads + 255) / 256, 256, 0, stream>>>(h, W1_w, hb, Wb, M);

    // gemm: 392 m-chunks x 8 n-blocks, XCD-paired encoding
    int nbx = ((M + BM - 1) / BM + 7) / 8 * 8;     // 392
    gemm_kernel<<<nbx * 8, 256, 0, stream>>>(hb, Wb, W1_b, C, M);

    edge_kernel<<<(E / 2 + 7) / 8, 256, 0, stream>>>(C, src, dst, W2_w, W2_b, out, E);
}

// Round 10
// 225.931 us; speedup vs baseline: 1.2087x; 1.0048x over previous
//
#include <hip/hip_runtime.h>

#define F 256
#define TWO_F 512
#define BM 128
#define BN 64
#define BK 64

typedef __attribute__((ext_vector_type(8))) short short8;
typedef __attribute__((ext_vector_type(4))) float float4v;

// ---------- bf16 helpers ----------
static __device__ __forceinline__ unsigned short f2bf(float f) {
    unsigned u = __float_as_uint(f);
    u += 0x7FFFu + ((u >> 16) & 1u);
    return (unsigned short)(u >> 16);
}
// pack two floats -> two bf16 (round-half-up) in 2 adds + 1 v_perm
static __device__ __forceinline__ unsigned pack2(float lo, float hi) {
    unsigned a = __float_as_uint(lo) + 0x8000u;
    unsigned b = __float_as_uint(hi) + 0x8000u;
    return __builtin_amdgcn_perm(b, a, 0x07060302u);
}
static __device__ __forceinline__ float blo(unsigned u) { return __uint_as_float(u << 16); }
static __device__ __forceinline__ float rawf(unsigned u) { return __uint_as_float(u); }

// ---------- kernel 1 (merged prep): h fp32->hb bf16 and W1 fp32->Wb bf16, both k-rotated ----------
// rotation: within each 64-elem k-block, elem k -> (k + (row&7)*8) & 63  (row = m for hb, n for Wb)
__global__ __launch_bounds__(256) void prep_kernel(
    const float* __restrict__ h, const float* __restrict__ W1,
    unsigned short* __restrict__ hb, unsigned short* __restrict__ Wb, int M)
{
    int i = blockIdx.x * blockDim.x + threadIdx.x;
    if (i < M * 128) {                       // h part: one bf16 pair per thread
        int m = i >> 7;
        int kp = (i & 127) * 2;
        float2 v = *(const float2*)(h + (size_t)m * F + kp);
        unsigned pk = pack2(v.x, v.y);
        int ksw = ((kp & 63) + (m & 7) * 8) & 63;   // rotation multiple of 8 -> pair intact
        *(unsigned*)(hb + (size_t)m * F + (kp & ~63) + ksw) = pk;
    }
    if (i < TWO_F * F) {                     // W part: one elem per thread (first 512 blocks)
        int n = i >> 8;
        int k = i & 255;
        float v = W1[(n & 255) * TWO_F + ((n >> 8) << 8) + k];
        int kin_sw = ((k & 63) + (n & 7) * 8) & 63;
        Wb[n * F + (k & ~63) + kin_sw] = f2bf(v);
    }
}

// ---------- kernel 2: C[m][n] = sum_k hb[m][k]*Wb[n][k] (+b1 for n<256), bf16 out ----------
// BM=128 x BN=64, 24 KB LDS, 4 blocks/CU. Wave self-stages its own 32 m-rows of sA.
// Epilogue: acc -> sA (bf16 tile) -> coalesced uint4 stores.
// NOTE (session record): six GEMM structures tested (per-K-barrier, persistent-W,
// stage-ahead dbuf, barrier-free reg-direct, reg-dbuf, pinned counted-vmcnt) all land at
// 85-100us with MfmaUtil ~6% / VALUBusy ~12% / HBM ~11% / 0 bank conflicts -> skinny-K
// (4 K-steps) latency floor, not schedule-limited. This variant is the measured best.
__global__ __launch_bounds__(256, 4) void gemm_kernel(
    const unsigned short* __restrict__ hb, const unsigned short* __restrict__ Wb,
    const float* __restrict__ b1v, unsigned short* __restrict__ C, int M)
{
    __shared__ unsigned short sA[BM * BK];   // 16 KB (K-loop A tile; reused as C tile in epilogue)
    __shared__ unsigned short sB[BN * BK];   //  8 KB

    // XCD pairing: all 8 by-blocks of one bx share (ib&7) -> same XCD -> h strip L2-reused 8x.
    const int ib = blockIdx.x;
    const int r8 = ib & 7;
    const int q  = ib >> 3;
    const int by = q & 7;
    const int bx = (q >> 3) * 8 + r8;
    const int bm = bx * BM;
    if (bm >= M) return;
    const int bn = by * BN;

    const int tid  = threadIdx.x;
    const int lane = tid & 63;
    const int wid  = tid >> 6;
    const int st_r = lane >> 3;
    const int st_k = (lane & 7) * 8;
    const int quad = lane >> 4;
    const int l15  = lane & 15;
    const int rot  = (l15 & 7) * 8;

    float4v acc[2][4];
    #pragma unroll
    for (int i = 0; i < 2; ++i)
        #pragma unroll
        for (int j = 0; j < 4; ++j) acc[i][j] = (float4v)(0.f);

    for (int k0 = 0; k0 < F; k0 += BK) {
        // sA: wave stages its own m-strip rows wid*32 .. +31 (4 issues x 8 rows)
        #pragma unroll
        for (int p = 0; p < 4; ++p) {
            int r = wid * 32 + p * 8;
            int am = bm + r + st_r; if (am > M - 1) am = M - 1;   // clamp; stores guarded
            const unsigned short* ga = hb + (size_t)am * F + k0 + st_k;
            __builtin_amdgcn_global_load_lds(
                (const __attribute__((address_space(1))) unsigned int*)ga,
                (__attribute__((address_space(3))) unsigned int*)&sA[r * BK],
                16, 0, 0);
        }
        // sB: wave stages rows wid*16 .. +15 (2 issues x 8 rows)
        #pragma unroll
        for (int p = 0; p < 2; ++p) {
            int r = wid * 16 + p * 8;
            const unsigned short* gb = Wb + (size_t)(bn + r + st_r) * F + k0 + st_k;
            __builtin_amdgcn_global_load_lds(
                (const __attribute__((address_space(1))) unsigned int*)gb,
                (__attribute__((address_space(3))) unsigned int*)&sB[r * BK],
                16, 0, 0);
        }
        __syncthreads();

        #pragma unroll
        for (int ks = 0; ks < 2; ++ks) {
            const int koff = (ks * 32 + quad * 8 + rot) & 63;
            short8 afr[2], bfr[4];
            #pragma unroll
            for (int mt = 0; mt < 2; ++mt)
                afr[mt] = *(const short8*)&sA[(wid * 32 + mt * 16 + l15) * BK + koff];
            #pragma unroll
            for (int nt = 0; nt < 4; ++nt)
                bfr[nt] = *(const short8*)&sB[(nt * 16 + l15) * BK + koff];
            #pragma unroll
            for (int mt = 0; mt < 2; ++mt)
                #pragma unroll
                for (int nt = 0; nt < 4; ++nt)
                    acc[mt][nt] = __builtin_amdgcn_mfma_f32_16x16x32_bf16(
                        afr[mt], bfr[nt], acc[mt][nt], 0, 0, 0);
        }
        __syncthreads();
    }
    // loop ends with __syncthreads(): all waves done reading sA/sB -> safe to reuse sA

    // epilogue: +b1 for the n<256 half, pack to bf16 tile in sA, coalesced store
    float bias[4];
    #pragma unroll
    for (int nt = 0; nt < 4; ++nt) {
        int n = bn + nt * 16 + l15;
        bias[nt] = (n < F) ? b1v[n] : 0.f;
    }
    #pragma unroll
    for (int mt = 0; mt < 2; ++mt) {
        #pragma unroll
        for (int rr = 0; rr < 4; ++rr) {
            int row = wid * 32 + mt * 16 + quad * 4 + rr;
            #pragma unroll
            for (int nt = 0; nt < 4; ++nt)
                sA[row * BK + nt * 16 + l15] = f2bf(acc[mt][nt][rr] + bias[nt]);
        }
    }
    __syncthreads();
    // 128 rows x 64 cols (128 B/row): 8 threads x 16 B per row, 32 rows per round, 4 rounds
    #pragma unroll
    for (int p = 0; p < 4; ++p) {
        int row = p * 32 + (tid >> 3);
        int gm = bm + row;
        if (gm < M) {
            uint4 v = *(const uint4*)&sA[row * BK + (tid & 7) * 8];
            *(uint4*)(C + (size_t)gm * TWO_F + bn + (tid & 7) * 8) = v;
        }
    }
}

// ---------- kernel 3: per-edge score, 2 edges per 32-lane group ----------
// Unsorted gather: sorted variants cut edge time 104->72us but the sort+overhead
// (~25-30us) cancels it exactly; this 3-dispatch pipeline is the measured optimum.
__global__ __launch_bounds__(256) void edge_kernel(
    const unsigned short* __restrict__ C,
    const int* __restrict__ src, const int* __restrict__ dst,
    const float* __restrict__ w2,
    const float* __restrict__ b2, float* __restrict__ out, int E)
{
    const int lane = threadIdx.x & 31;
    const int g = blockIdx.x * 8 + (threadIdx.x >> 5);
    const int e0 = g * 2;
    if (e0 >= E) return;
    const int s0 = src[e0], d0 = dst[e0];
    const int s1 = src[e0 + 1], d1 = dst[e0 + 1];

    uint4 av0 = *(const uint4*)(C + (size_t)s0 * TWO_F + lane * 8);
    uint4 bv0 = *(const uint4*)(C + (size_t)d0 * TWO_F + F + lane * 8);
    uint4 av1 = *(const uint4*)(C + (size_t)s1 * TWO_F + lane * 8);
    uint4 bv1 = *(const uint4*)(C + (size_t)d1 * TWO_F + F + lane * 8);
    float4 w0 = *(const float4*)(w2 + lane * 8);
    float4 w1 = *(const float4*)(w2 + lane * 8 + 4);

    float sum0, sum1;
    sum0  = w0.x * fmaxf(blo(av0.x) + blo(bv0.x), 0.f);
    sum0 += w0.y * fmaxf(rawf(av0.x) + rawf(bv0.x), 0.f);
    sum0 += w0.z * fmaxf(blo(av0.y) + blo(bv0.y), 0.f);
    sum0 += w0.w * fmaxf(rawf(av0.y) + rawf(bv0.y), 0.f);
    sum0 += w1.x * fmaxf(blo(av0.z) + blo(bv0.z), 0.f);
    sum0 += w1.y * fmaxf(rawf(av0.z) + rawf(bv0.z), 0.f);
    sum0 += w1.z * fmaxf(blo(av0.w) + blo(bv0.w), 0.f);
    sum0 += w1.w * fmaxf(rawf(av0.w) + rawf(bv0.w), 0.f);

    sum1  = w0.x * fmaxf(blo(av1.x) + blo(bv1.x), 0.f);
    sum1 += w0.y * fmaxf(rawf(av1.x) + rawf(bv1.x), 0.f);
    sum1 += w0.z * fmaxf(blo(av1.y) + blo(bv1.y), 0.f);
    sum1 += w0.w * fmaxf(rawf(av1.y) + rawf(bv1.y), 0.f);
    sum1 += w1.x * fmaxf(blo(av1.z) + blo(bv1.z), 0.f);
    sum1 += w1.y * fmaxf(rawf(av1.z) + rawf(bv1.z), 0.f);
    sum1 += w1.z * fmaxf(blo(av1.w) + blo(bv1.w), 0.f);
    sum1 += w1.w * fmaxf(rawf(av1.w) + rawf(bv1.w), 0.f);

    #pragma unroll
    for (int off = 16; off > 0; off >>= 1) {
        sum0 += __shfl_down(sum0, off, 32);
        sum1 += __shfl_down(sum1, off, 32);
    }

    if (lane == 0) {
        float b = b2[0];
        out[e0]     = sum0 + b;
        out[e0 + 1] = sum1 + b;
    }
}

extern "C" void kernel_launch(void* const* d_in, const int* in_sizes, int n_in,
                              void* d_out, int out_size, void* d_ws, size_t ws_size,
                              hipStream_t stream) {
    const float* h    = (const float*)d_in[0];
    const int*   src  = (const int*)d_in[1];
    const int*   dst  = (const int*)d_in[2];
    const float* W1_w = (const float*)d_in[3];
    const float* W1_b = (const float*)d_in[4];
    const float* W2_w = (const float*)d_in[5];
    const float* W2_b = (const float*)d_in[6];
    float* out = (float*)d_out;

    const int M = in_sizes[0] / F;   // 50000
    const int E = in_sizes[1];       // 800000

    // ws: [Wb bf16 256KB][pad to 512KB][hb bf16 25.6MB, pad to 26MB][C bf16 51.2MB]
    unsigned short* Wb = (unsigned short*)d_ws;
    unsigned short* hb = (unsigned short*)((char*)d_ws + 512 * 1024);
    unsigned short* C  = (unsigned short*)((char*)d_ws + 512 * 1024 + 26 * 1024 * 1024);

    // merged prep: grid covers both h pairs (M*128 threads) and W elems (131072 threads)
    int prep_threads = M * 128 > TWO_F * F ? M * 128 : TWO_F * F;
    prep_kernel<<<(prep_threads + 255) / 256, 256, 0, stream>>>(h, W1_w, hb, Wb, M);

    // grid: 392 m-chunks x 8 n-blocks, XCD-paired encoding
    int nbx = ((M + BM - 1) / BM + 7) / 8 * 8;     // 392
    gemm_kernel<<<nbx * 8, 256, 0, stream>>>(hb, Wb, W1_b, C, M);

    edge_kernel<<<(E / 2 + 7) / 8, 256, 0, stream>>>(C, src, dst, W2_w, W2_b, out, E);
}